// Round 1
// baseline (161.318 us; speedup 1.0000x reference)
//
#include <hip/hip_runtime.h>

// LocalEnergyOpt: bonded force-field energy (bonds + angles + torsions)
// B=256 systems, one block per system. Memory-bound on the 92MB features
// tensor (stride-9 column layout). Coords staged to LDS; params pre-resolved.

#define BS 512

__global__ __launch_bounds__(BS) void energy_kernel(
    const float* __restrict__ features,   // [B, 10000, 9]
    const int*   __restrict__ lengths,    // [B, 9]
    const float* __restrict__ opt_pars,   // [350, 3]
    const float* __restrict__ bond_type,  // [50]
    const float* __restrict__ angle_type, // [100]
    const float* __restrict__ tor_type,   // [200]
    float*       __restrict__ out)        // [B]
{
    constexpr int MAXLEN  = 10000;
    constexpr int N_ATOMS = 2000;
    constexpr int NBT = 50, NAT = 100, NTT = 200;
    constexpr float EPS = 1e-8f;

    const int b   = blockIdx.x;
    const int tid = threadIdx.x;
    const float* __restrict__ fb = features + (size_t)b * MAXLEN * 9;

    __shared__ float sc[3 * N_ATOMS];   // coords, flat [atom*3 + d] (24 KB)
    __shared__ float sbp[3 * NBT];      // resolved bond params  (k, r0, n)
    __shared__ float sap[3 * NAT];      // resolved angle params
    __shared__ float stp[3 * NTT];      // resolved torsion params
    __shared__ float swsum[BS / 64];

    // ---- stage coords: features[b, i, 5] for i in [0, 6000) ----
    for (int i = tid; i < 3 * N_ATOMS; i += BS)
        sc[i] = fb[i * 9 + 5];

    // ---- stage resolved param tables: opt_pars[map[t]] ----
    for (int i = tid; i < NBT; i += BS) {
        int idx = (int)bond_type[i];
        sbp[3*i+0] = opt_pars[3*idx+0];
        sbp[3*i+1] = opt_pars[3*idx+1];
        sbp[3*i+2] = opt_pars[3*idx+2];
    }
    for (int i = tid; i < NAT; i += BS) {
        int idx = (int)angle_type[i];
        sap[3*i+0] = opt_pars[3*idx+0];
        sap[3*i+1] = opt_pars[3*idx+1];
        sap[3*i+2] = opt_pars[3*idx+2];
    }
    for (int i = tid; i < NTT; i += BS) {
        int idx = (int)tor_type[i];
        stp[3*i+0] = opt_pars[3*idx+0];
        stp[3*i+1] = opt_pars[3*idx+1];
        stp[3*i+2] = opt_pars[3*idx+2];
    }
    __syncthreads();

    float acc = 0.0f;

    // ---- bonds: E = k * (r - r0)^2 ----
    {
        const int nb = lengths[b * 9 + 6] / 3;
        const float* __restrict__ c6 = fb + 6;
        for (int t = tid; t < nb; t += BS) {
            const int base = 27 * t;
            int i  = (int)c6[base];
            int j  = (int)c6[base + 9];
            int ty = (int)c6[base + 18];
            float dx = sc[3*i+0] - sc[3*j+0];
            float dy = sc[3*i+1] - sc[3*j+1];
            float dz = sc[3*i+2] - sc[3*j+2];
            float r  = sqrtf(dx*dx + dy*dy + dz*dz + EPS);
            float k  = sbp[3*ty+0];
            float d  = r - sbp[3*ty+1];
            acc += k * d * d;
        }
    }

    // ---- angles: E = k * (theta - theta0)^2 ----
    {
        const int na = lengths[b * 9 + 7] / 4;
        const float* __restrict__ c7 = fb + 7;
        for (int t = tid; t < na; t += BS) {
            const int base = 36 * t;
            int i  = (int)c7[base];
            int j  = (int)c7[base + 9];
            int k_ = (int)c7[base + 18];
            int ty = (int)c7[base + 27];
            float jx = sc[3*j+0], jy = sc[3*j+1], jz = sc[3*j+2];
            float ux = sc[3*i+0] - jx, uy = sc[3*i+1] - jy, uz = sc[3*i+2] - jz;
            float vx = sc[3*k_+0] - jx, vy = sc[3*k_+1] - jy, vz = sc[3*k_+2] - jz;
            float uv = ux*vx + uy*vy + uz*vz;
            float uu = ux*ux + uy*uy + uz*uz;
            float vv = vx*vx + vy*vy + vz*vz;
            float c  = uv * rsqrtf((uu + EPS) * (vv + EPS));
            c = fminf(fmaxf(c, -1.0f + 1e-6f), 1.0f - 1e-6f);
            float theta = acosf(c);
            float k  = sap[3*ty+0];
            float d  = theta - sap[3*ty+1];
            acc += k * d * d;
        }
    }

    // ---- torsions: E = k * (1 + cos(n*phi - phi0)) ----
    {
        const int nt = lengths[b * 9 + 8] / 5;
        const float* __restrict__ c8 = fb + 8;
        for (int t = tid; t < nt; t += BS) {
            const int base = 45 * t;
            int i  = (int)c8[base];
            int j  = (int)c8[base + 9];
            int k_ = (int)c8[base + 18];
            int l  = (int)c8[base + 27];
            int ty = (int)c8[base + 36];
            float ix = sc[3*i+0],  iy = sc[3*i+1],  iz = sc[3*i+2];
            float jx = sc[3*j+0],  jy = sc[3*j+1],  jz = sc[3*j+2];
            float kx = sc[3*k_+0], ky = sc[3*k_+1], kz = sc[3*k_+2];
            float lx = sc[3*l+0],  ly = sc[3*l+1],  lz = sc[3*l+2];
            float b1x = jx - ix, b1y = jy - iy, b1z = jz - iz;
            float b2x = kx - jx, b2y = ky - jy, b2z = kz - jz;
            float b3x = lx - kx, b3y = ly - ky, b3z = lz - kz;
            // n1 = b1 x b2 ; n2 = b2 x b3
            float n1x = b1y*b2z - b1z*b2y;
            float n1y = b1z*b2x - b1x*b2z;
            float n1z = b1x*b2y - b1y*b2x;
            float n2x = b2y*b3z - b2z*b3y;
            float n2y = b2z*b3x - b2x*b3z;
            float n2z = b2x*b3y - b2y*b3x;
            float inv = rsqrtf(b2x*b2x + b2y*b2y + b2z*b2z + EPS);
            float hx = b2x * inv, hy = b2y * inv, hz = b2z * inv;
            // m1 = n1 x b2h
            float m1x = n1y*hz - n1z*hy;
            float m1y = n1z*hx - n1x*hz;
            float m1z = n1x*hy - n1y*hx;
            float sy = m1x*n2x + m1y*n2y + m1z*n2z;
            float sx = n1x*n2x + n1y*n2y + n1z*n2z;
            float phi = atan2f(sy, sx);
            float k  = stp[3*ty+0];
            float p0 = stp[3*ty+1];
            float n  = stp[3*ty+2];
            acc += k * (1.0f + cosf(n * phi - p0));
        }
    }

    // ---- reduce: wave (64-lane) shuffle, then cross-wave via LDS ----
    for (int off = 32; off > 0; off >>= 1)
        acc += __shfl_down(acc, off, 64);
    const int wave = tid >> 6, lane = tid & 63;
    if (lane == 0) swsum[wave] = acc;
    __syncthreads();
    if (tid == 0) {
        float s = 0.0f;
        #pragma unroll
        for (int w = 0; w < BS / 64; ++w) s += swsum[w];
        out[b] = s;
    }
}

extern "C" void kernel_launch(void* const* d_in, const int* in_sizes, int n_in,
                              void* d_out, int out_size, void* d_ws, size_t ws_size,
                              hipStream_t stream) {
    const float* features   = (const float*)d_in[0];
    const int*   lengths    = (const int*)  d_in[1];
    const float* opt_pars   = (const float*)d_in[2];
    const float* bond_type  = (const float*)d_in[3];
    const float* angle_type = (const float*)d_in[4];
    const float* tor_type   = (const float*)d_in[5];
    float* out = (float*)d_out;

    const int B = out_size;  // 256
    energy_kernel<<<B, BS, 0, stream>>>(features, lengths, opt_pars,
                                        bond_type, angle_type, tor_type, out);
}